// Round 2
// baseline (293.080 us; speedup 1.0000x reference)
//
#include <hip/hip_runtime.h>
#include <math.h>

namespace {

constexpr int   kB     = 16;
constexpr int   kA     = 65536;
constexpr int   kM     = 32;
constexpr int   kC     = 20;
constexpr float kImg   = 600.0f;
constexpr int   kBlock = 256;
constexpr int   kAnch  = 4;      // anchors per thread

__device__ __forceinline__ float smooth_l1(float d) {
    float ad = fabsf(d);
    return ad < 1.0f ? 0.5f * d * d : ad - 0.5f;
}

__global__ __launch_bounds__(kBlock, 3) void retina_main(
    const float* __restrict__ loc_preds,   // [B, A, 4]
    const float* __restrict__ cls_preds,   // [B, A, C]
    const float* __restrict__ iou_boxes,   // [A, 4] xywh
    const float* __restrict__ targets,     // [B*M, 6]
    float* __restrict__ acc)               // acc[0]=loc acc[1]=cls acc[2]=npos
{
    __shared__ float4 sbox[kM];    // x1, y1, x2+1, y2+1 (pixels)
    __shared__ float4 sxywh[kM];   // cx, cy, w, h (pixels)
    __shared__ float  sarea[kM];   // target area (with +1)
    __shared__ int    slab[kM];
    __shared__ float  sred[3][kBlock / 64];

    const int b     = blockIdx.y;
    const int abase = blockIdx.x * (kBlock * kAnch) + threadIdx.x;

    if (threadIdx.x < kM) {
        const float* t = targets + ((size_t)(b * kM + threadIdx.x)) * 6;
        float cx = t[2] * kImg, cy = t[3] * kImg;
        float w  = t[4] * kImg, h  = t[5] * kImg;
        float x1 = cx - w * 0.5f, y1 = cy - h * 0.5f;
        float x2p = cx + w * 0.5f + 1.0f, y2p = cy + h * 0.5f + 1.0f;
        sbox[threadIdx.x]  = make_float4(x1, y1, x2p, y2p);
        sxywh[threadIdx.x] = make_float4(cx, cy, w, h);
        sarea[threadIdx.x] = (x2p - x1) * (y2p - y1);
        slab[threadIdx.x]  = (int)t[1];
    }
    __syncthreads();

    // ---- Preload all global payload (max MLP): anchors, loc, cls ----
    float4 an[kAnch], lp[kAnch], cv[kAnch][kC / 4];
#pragma unroll
    for (int k = 0; k < kAnch; ++k) {
        const int a = abase + k * kBlock;
        an[k] = *(const float4*)(iou_boxes + (size_t)a * 4);
        lp[k] = *(const float4*)(loc_preds + ((size_t)b * kA + a) * 4);
#pragma unroll
        for (int i = 0; i < kC / 4; ++i)
            cv[k][i] = *(const float4*)(cls_preds + ((size_t)b * kA + a) * kC + i * 4);
    }

    // ---- Anchor geometry ----
    float ax1[kAnch], ay1[kAnch], ax2p[kAnch], ay2p[kAnch], aarea[kAnch];
#pragma unroll
    for (int k = 0; k < kAnch; ++k) {
        ax1[k]  = an[k].x - an[k].z * 0.5f;
        ay1[k]  = an[k].y - an[k].w * 0.5f;
        ax2p[k] = an[k].x + an[k].z * 0.5f + 1.0f;
        ay2p[k] = an[k].y + an[k].w * 0.5f + 1.0f;
        aarea[k] = (ax2p[k] - ax1[k]) * (ay2p[k] - ay1[k]);
    }

    // ---- IoU argmax: one LDS read feeds 4 independent chains ----
    float best[kAnch];
    int   mid[kAnch];
#pragma unroll
    for (int k = 0; k < kAnch; ++k) { best[k] = -1.0f; mid[k] = 0; }

#pragma unroll
    for (int m = 0; m < kM; ++m) {
        const float4 q  = sbox[m];
        const float  ta = sarea[m];
#pragma unroll
        for (int k = 0; k < kAnch; ++k) {
            float lx = fmaxf(ax1[k],  q.x);
            float ly = fmaxf(ay1[k],  q.y);
            float rx = fminf(ax2p[k], q.z);
            float ry = fminf(ay2p[k], q.w);
            float w  = fmaxf(rx - lx, 0.0f);
            float h  = fmaxf(ry - ly, 0.0f);
            float inter = w * h;
            float uni   = aarea[k] + ta - inter;
            float iou   = inter * __builtin_amdgcn_rcpf(uni);
            if (iou > best[k]) { best[k] = iou; mid[k] = m; }
        }
    }

    float loc_sum = 0.0f, cls_sum = 0.0f, npos = 0.0f;

#pragma unroll
    for (int k = 0; k < kAnch; ++k) {
        const bool pos = best[k] >= 0.5f;
        const bool ign = (best[k] > 0.4f) && !pos;

        // ---- SmoothL1 (positives only; load already done) ----
        if (pos) {
            npos += 1.0f;
            float4 mb = sxywh[mid[k]];
            float ltx = (mb.x - an[k].x) * __builtin_amdgcn_rcpf(an[k].z);
            float lty = (mb.y - an[k].y) * __builtin_amdgcn_rcpf(an[k].w);
            float ltw = __logf(mb.z * __builtin_amdgcn_rcpf(an[k].z));
            float lth = __logf(mb.w * __builtin_amdgcn_rcpf(an[k].w));
            loc_sum += smooth_l1(lp[k].x - ltx) + smooth_l1(lp[k].y - lty) +
                       smooth_l1(lp[k].z - ltw) + smooth_l1(lp[k].w - lth);
        }

        // ---- Focal: alpha_t * sigmoid(z)^2 * softplus(z), z = t ? -x : x ----
        const int tgt = pos ? (slab[mid[k]] + 1) : 0;
        float csum = 0.0f;
#pragma unroll
        for (int i = 0; i < kC / 4; ++i) {
            float xs[4] = {cv[k][i].x, cv[k][i].y, cv[k][i].z, cv[k][i].w};
#pragma unroll
            for (int j = 0; j < 4; ++j) {
                float x = xs[j];
                bool  t = (i * 4 + j + 1) == tgt;
                float z = t ? -x : x;
                float e = __expf(-fabsf(z));                  // exp(-|z|)
                float r = __builtin_amdgcn_rcpf(1.0f + e);
                float sig = (z >= 0.0f) ? r : e * r;          // sigmoid(z) = 1-pt
                float sp  = __logf(1.0f + e) + fmaxf(z, 0.0f); // softplus(z) = bce
                float al  = t ? 0.25f : 0.75f;
                csum += al * sig * sig * sp;
            }
        }
        cls_sum += ign ? 0.0f : csum;
    }

    // ---- Reduce: wave shuffle -> LDS -> one atomic per block ----
#pragma unroll
    for (int off = 32; off > 0; off >>= 1) {
        loc_sum += __shfl_down(loc_sum, off);
        cls_sum += __shfl_down(cls_sum, off);
        npos    += __shfl_down(npos, off);
    }
    const int lane = threadIdx.x & 63;
    const int wid  = threadIdx.x >> 6;
    if (lane == 0) {
        sred[0][wid] = loc_sum;
        sred[1][wid] = cls_sum;
        sred[2][wid] = npos;
    }
    __syncthreads();
    if (threadIdx.x == 0) {
        float l = 0.0f, c = 0.0f, n = 0.0f;
#pragma unroll
        for (int i = 0; i < kBlock / 64; ++i) {
            l += sred[0][i]; c += sred[1][i]; n += sred[2][i];
        }
        atomicAdd(acc + 0, l);
        atomicAdd(acc + 1, c);
        atomicAdd(acc + 2, n);
    }
}

__global__ void retina_final(const float* __restrict__ acc, float* __restrict__ out) {
    float loc = acc[0], cls = acc[1];
    float np  = fmaxf(1.0f, acc[2]);
    float inv = 1.0f / np;
    out[0] = (loc + cls) * inv;
    out[1] = loc * inv;
    out[2] = cls * inv;
}

}  // namespace

extern "C" void kernel_launch(void* const* d_in, const int* in_sizes, int n_in,
                              void* d_out, int out_size, void* d_ws, size_t ws_size,
                              hipStream_t stream) {
    const float* loc_preds = (const float*)d_in[0];
    const float* cls_preds = (const float*)d_in[1];
    const float* iou_boxes = (const float*)d_in[2];
    const float* targets   = (const float*)d_in[3];
    float* out = (float*)d_out;
    float* acc = (float*)d_ws;

    hipMemsetAsync(acc, 0, 3 * sizeof(float), stream);

    dim3 grid(kA / (kBlock * kAnch), kB);
    retina_main<<<grid, kBlock, 0, stream>>>(loc_preds, cls_preds, iou_boxes, targets, acc);
    retina_final<<<1, 1, 0, stream>>>(acc, out);
}

// Round 3
// 208.484 us; speedup vs baseline: 1.4058x; 1.4058x over previous
//
#include <hip/hip_runtime.h>
#include <math.h>

namespace {

constexpr int   kB     = 16;
constexpr int   kA     = 65536;
constexpr int   kM     = 32;
constexpr int   kC     = 20;
constexpr float kImg   = 600.0f;
constexpr int   kBlock = 256;
constexpr int   kF4PerAnchor = kC / 4;          // 5
constexpr int   kGridX = kA / kBlock;           // 256
constexpr int   kNBlocks = kGridX * kB;         // 4096

__device__ __forceinline__ float smooth_l1(float d) {
    float ad = fabsf(d);
    return ad < 1.0f ? 0.5f * d * d : ad - 0.5f;
}

__global__ __launch_bounds__(kBlock, 4) void retina_main(
    const float* __restrict__ loc_preds,   // [B, A, 4]
    const float* __restrict__ cls_preds,   // [B, A, C]
    const float* __restrict__ iou_boxes,   // [A, 4] xywh
    const float* __restrict__ targets,     // [B*M, 6]
    float* __restrict__ partial)           // [kNBlocks][3]
{
    __shared__ float4 sbox[kM];    // x1, y1, x2+1, y2+1 (pixels)
    __shared__ float4 sxywh[kM];   // cx, cy, w, h (pixels)
    __shared__ float  sarea[kM];   // target area (+1 convention)
    __shared__ int    slab[kM];
    __shared__ int    scode[kBlock];  // per-anchor: -1 ignored, else tgt in [0,20]
    __shared__ float  sred[3][kBlock / 64];

    const int b  = blockIdx.y;
    const int ab = blockIdx.x * kBlock;   // block's first anchor
    const int a  = ab + threadIdx.x;

    if (threadIdx.x < kM) {
        const float* t = targets + ((size_t)(b * kM + threadIdx.x)) * 6;
        float cx = t[2] * kImg, cy = t[3] * kImg;
        float w  = t[4] * kImg, h  = t[5] * kImg;
        float x1  = cx - w * 0.5f,        y1  = cy - h * 0.5f;
        float x2p = cx + w * 0.5f + 1.0f, y2p = cy + h * 0.5f + 1.0f;
        sbox[threadIdx.x]  = make_float4(x1, y1, x2p, y2p);
        sxywh[threadIdx.x] = make_float4(cx, cy, w, h);
        sarea[threadIdx.x] = (x2p - x1) * (y2p - y1);
        slab[threadIdx.x]  = (int)t[1];
    }

    // ---- Issue ALL global loads up front (single memory epoch, coalesced) ----
    const float4 an = *(const float4*)(iou_boxes + (size_t)a * 4);
    const float4 lp = *(const float4*)(loc_preds + ((size_t)b * kA + a) * 4);
    // Block-contiguous cls slab: [ab*20, (ab+256)*20) floats; thread reads 5
    // lane-contiguous float4 (perfectly coalesced, NOT its own anchor's row).
    const float* cp0 = cls_preds + ((size_t)b * kA + ab) * kC;
    float4 cv[kF4PerAnchor];
#pragma unroll
    for (int i = 0; i < kF4PerAnchor; ++i)
        cv[i] = *(const float4*)(cp0 + (i * kBlock + threadIdx.x) * 4);

    __syncthreads();

    // ---- Phase 1: IoU argmax for this thread's anchor ----
    const float ax1  = an.x - an.z * 0.5f;
    const float ay1  = an.y - an.w * 0.5f;
    const float ax2p = an.x + an.z * 0.5f + 1.0f;
    const float ay2p = an.y + an.w * 0.5f + 1.0f;
    const float aarea = (ax2p - ax1) * (ay2p - ay1);

    float best = -1.0f;
    int   mid  = 0;
#pragma unroll
    for (int m = 0; m < kM; ++m) {
        float4 q = sbox[m];
        float lx = fmaxf(ax1,  q.x);
        float ly = fmaxf(ay1,  q.y);
        float rx = fminf(ax2p, q.z);
        float ry = fminf(ay2p, q.w);
        float w  = fmaxf(rx - lx, 0.0f);
        float h  = fmaxf(ry - ly, 0.0f);
        float inter = w * h;
        float uni   = aarea + sarea[m] - inter;
        float iou   = inter * __builtin_amdgcn_rcpf(uni);
        if (iou > best) { best = iou; mid = m; }
    }

    const bool pos = best >= 0.5f;
    const bool ign = (best > 0.4f) && !pos;

    float loc_sum = 0.0f, npos = 0.0f;
    if (pos) {
        npos = 1.0f;
        float4 mb = sxywh[mid];
        float ltx = (mb.x - an.x) * __builtin_amdgcn_rcpf(an.z);
        float lty = (mb.y - an.y) * __builtin_amdgcn_rcpf(an.w);
        float ltw = __logf(mb.z * __builtin_amdgcn_rcpf(an.z));
        float lth = __logf(mb.w * __builtin_amdgcn_rcpf(an.w));
        loc_sum = smooth_l1(lp.x - ltx) + smooth_l1(lp.y - lty) +
                  smooth_l1(lp.z - ltw) + smooth_l1(lp.w - lth);
    }

    scode[threadIdx.x] = ign ? -1 : (pos ? slab[mid] + 1 : 0);
    __syncthreads();

    // ---- Phase 2: focal over the block's cls slab (already in registers) ----
    // float4 index f in [0,1280): anchor_local = f/5, class_base = (f%5)*4.
    float cls_sum = 0.0f;
#pragma unroll
    for (int i = 0; i < kF4PerAnchor; ++i) {
        const int f  = i * kBlock + threadIdx.x;
        const int al = f / 5;               // anchor local (magic-mul)
        const int cb = (f - al * 5) * 4;    // class base: 0,4,8,12,16
        const int code = scode[al];         // -1 ignored; 0 bg; 1..20 class+1
        const float live = (code >= 0) ? 1.0f : 0.0f;
        float xs[4] = {cv[i].x, cv[i].y, cv[i].z, cv[i].w};
        float csum = 0.0f;
#pragma unroll
        for (int j = 0; j < 4; ++j) {
            float x = xs[j];
            bool  t = (cb + j + 1) == code;
            float z = t ? -x : x;
            float e = __expf(-fabsf(z));                   // exp(-|z|)
            float r = __builtin_amdgcn_rcpf(1.0f + e);
            float sig = (z >= 0.0f) ? r : e * r;           // sigmoid(z) = 1-pt
            float sp  = __logf(1.0f + e) + fmaxf(z, 0.0f); // softplus(z) = bce
            float alw = t ? 0.25f : 0.75f;
            csum += alw * sig * sig * sp;
        }
        cls_sum += live * csum;
    }

    // ---- Reduce: wave shuffle -> LDS -> per-block partial (no atomics) ----
#pragma unroll
    for (int off = 32; off > 0; off >>= 1) {
        loc_sum += __shfl_down(loc_sum, off);
        cls_sum += __shfl_down(cls_sum, off);
        npos    += __shfl_down(npos, off);
    }
    const int lane = threadIdx.x & 63;
    const int wid  = threadIdx.x >> 6;
    if (lane == 0) {
        sred[0][wid] = loc_sum;
        sred[1][wid] = cls_sum;
        sred[2][wid] = npos;
    }
    __syncthreads();
    if (threadIdx.x == 0) {
        float l = 0.0f, c = 0.0f, n = 0.0f;
#pragma unroll
        for (int i = 0; i < kBlock / 64; ++i) {
            l += sred[0][i]; c += sred[1][i]; n += sred[2][i];
        }
        const int bid = blockIdx.y * gridDim.x + blockIdx.x;
        partial[3 * bid + 0] = l;
        partial[3 * bid + 1] = c;
        partial[3 * bid + 2] = n;
    }
}

__global__ __launch_bounds__(1024) void retina_final(
    const float* __restrict__ partial, float* __restrict__ out)
{
    __shared__ float s[3][16];
    float l = 0.0f, c = 0.0f, n = 0.0f;
    for (int i = threadIdx.x; i < kNBlocks; i += 1024) {
        l += partial[3 * i + 0];
        c += partial[3 * i + 1];
        n += partial[3 * i + 2];
    }
#pragma unroll
    for (int off = 32; off > 0; off >>= 1) {
        l += __shfl_down(l, off);
        c += __shfl_down(c, off);
        n += __shfl_down(n, off);
    }
    const int lane = threadIdx.x & 63;
    const int wid  = threadIdx.x >> 6;
    if (lane == 0) { s[0][wid] = l; s[1][wid] = c; s[2][wid] = n; }
    __syncthreads();
    if (threadIdx.x == 0) {
        float L = 0.0f, C = 0.0f, N = 0.0f;
#pragma unroll
        for (int i = 0; i < 16; ++i) { L += s[0][i]; C += s[1][i]; N += s[2][i]; }
        float np  = fmaxf(1.0f, N);
        float inv = 1.0f / np;
        out[0] = (L + C) * inv;
        out[1] = L * inv;
        out[2] = C * inv;
    }
}

}  // namespace

extern "C" void kernel_launch(void* const* d_in, const int* in_sizes, int n_in,
                              void* d_out, int out_size, void* d_ws, size_t ws_size,
                              hipStream_t stream) {
    const float* loc_preds = (const float*)d_in[0];
    const float* cls_preds = (const float*)d_in[1];
    const float* iou_boxes = (const float*)d_in[2];
    const float* targets   = (const float*)d_in[3];
    float* out     = (float*)d_out;
    float* partial = (float*)d_ws;   // 4096*3 floats, fully overwritten each call

    dim3 grid(kGridX, kB);
    retina_main<<<grid, kBlock, 0, stream>>>(loc_preds, cls_preds, iou_boxes, targets, partial);
    retina_final<<<1, 1024, 0, stream>>>(partial, out);
}

// Round 4
// 154.363 us; speedup vs baseline: 1.8986x; 1.3506x over previous
//
#include <hip/hip_runtime.h>
#include <math.h>

namespace {

constexpr int   kB     = 16;
constexpr int   kA     = 65536;
constexpr int   kM     = 32;
constexpr int   kC     = 20;
constexpr float kImg   = 600.0f;
constexpr int   kBlock = 256;
constexpr int   kF4PerAnchor = kC / 4;          // 5
constexpr int   kGridX = kA / kBlock;           // 256
constexpr int   kNBlocks = kGridX * kB;         // 4096

__device__ __forceinline__ float smooth_l1(float d) {
    float ad = fabsf(d);
    return ad < 1.0f ? 0.5f * d * d : ad - 0.5f;
}

__global__ __launch_bounds__(kBlock) void retina_main(
    const float* __restrict__ loc_preds,   // [B, A, 4]
    const float* __restrict__ cls_preds,   // [B, A, C]
    const float* __restrict__ iou_boxes,   // [A, 4] xywh
    const float* __restrict__ targets,     // [B*M, 6]
    float* __restrict__ partial)           // [kNBlocks][3]
{
    __shared__ float4 sbox[kM];    // x1, y1, x2+1, y2+1 (pixels)
    __shared__ float4 sxywh[kM];   // cx, cy, w, h (pixels)
    __shared__ float  sarea[kM];   // target area (+1 convention)
    __shared__ int    slab[kM];
    __shared__ int    scode[kBlock];  // per-anchor: -1 ignored, 0 bg, 1..20 cls+1
    __shared__ float  sred[3][kBlock / 64];

    const int b  = blockIdx.y;
    const int ab = blockIdx.x * kBlock;   // block's first anchor
    const int a  = ab + threadIdx.x;

    if (threadIdx.x < kM) {
        const float* t = targets + ((size_t)(b * kM + threadIdx.x)) * 6;
        float cx = t[2] * kImg, cy = t[3] * kImg;
        float w  = t[4] * kImg, h  = t[5] * kImg;
        float x1  = cx - w * 0.5f,        y1  = cy - h * 0.5f;
        float x2p = cx + w * 0.5f + 1.0f, y2p = cy + h * 0.5f + 1.0f;
        sbox[threadIdx.x]  = make_float4(x1, y1, x2p, y2p);
        sxywh[threadIdx.x] = make_float4(cx, cy, w, h);
        sarea[threadIdx.x] = (x2p - x1) * (y2p - y1);
        slab[threadIdx.x]  = (int)t[1];
    }

    // Phase-1 globals only (short live ranges): anchor + loc row.
    const float4 an = *(const float4*)(iou_boxes + (size_t)a * 4);
    const float4 lp = *(const float4*)(loc_preds + ((size_t)b * kA + a) * 4);

    __syncthreads();

    // ---- Phase 1: IoU argmax for this thread's anchor ----
    const float ax1  = an.x - an.z * 0.5f;
    const float ay1  = an.y - an.w * 0.5f;
    const float ax2p = an.x + an.z * 0.5f + 1.0f;
    const float ay2p = an.y + an.w * 0.5f + 1.0f;
    const float aarea = (ax2p - ax1) * (ay2p - ay1);

    float best = -1.0f;
    int   mid  = 0;
#pragma unroll
    for (int m = 0; m < kM; ++m) {
        float4 q = sbox[m];
        float lx = fmaxf(ax1,  q.x);
        float ly = fmaxf(ay1,  q.y);
        float rx = fminf(ax2p, q.z);
        float ry = fminf(ay2p, q.w);
        float w  = fmaxf(rx - lx, 0.0f);
        float h  = fmaxf(ry - ly, 0.0f);
        float inter = w * h;
        float uni   = aarea + sarea[m] - inter;
        float iou   = inter * __builtin_amdgcn_rcpf(uni);
        if (iou > best) { best = iou; mid = m; }
    }

    const bool pos = best >= 0.5f;
    const bool ign = (best > 0.4f) && !pos;

    float loc_sum = 0.0f, npos = 0.0f;
    if (pos) {
        npos = 1.0f;
        float4 mb = sxywh[mid];
        float ltx = (mb.x - an.x) * __builtin_amdgcn_rcpf(an.z);
        float lty = (mb.y - an.y) * __builtin_amdgcn_rcpf(an.w);
        float ltw = __logf(mb.z * __builtin_amdgcn_rcpf(an.z));
        float lth = __logf(mb.w * __builtin_amdgcn_rcpf(an.w));
        loc_sum = smooth_l1(lp.x - ltx) + smooth_l1(lp.y - lty) +
                  smooth_l1(lp.z - ltw) + smooth_l1(lp.w - lth);
    }

    scode[threadIdx.x] = ign ? -1 : (pos ? slab[mid] + 1 : 0);
    __syncthreads();

    // ---- Phase 2: focal over the block's contiguous cls slab ----
    // Loads issued HERE and consumed immediately: no barrier-crossing live
    // ranges -> no scratch spill (R3's 156 MB WRITE_SIZE).
    const float* cp0 = cls_preds + ((size_t)b * kA + ab) * kC;
    float4 cv[kF4PerAnchor];
#pragma unroll
    for (int i = 0; i < kF4PerAnchor; ++i)
        cv[i] = *(const float4*)(cp0 + (i * kBlock + threadIdx.x) * 4);

    float cls_sum = 0.0f;
#pragma unroll
    for (int i = 0; i < kF4PerAnchor; ++i) {
        const int f  = i * kBlock + threadIdx.x;
        const int al = f / 5;               // anchor local
        const int cb = (f - al * 5) * 4;    // class base: 0,4,8,12,16
        const int code = scode[al];
        const float live = (code >= 0) ? 1.0f : 0.0f;
        float xs[4] = {cv[i].x, cv[i].y, cv[i].z, cv[i].w};
        float csum = 0.0f;
#pragma unroll
        for (int j = 0; j < 4; ++j) {
            float x = xs[j];
            bool  t = (cb + j + 1) == code;
            float z = t ? -x : x;
            float e = __expf(-fabsf(z));                   // exp(-|z|)
            float r = __builtin_amdgcn_rcpf(1.0f + e);
            float sig = (z >= 0.0f) ? r : e * r;           // sigmoid(z) = 1-pt
            float sp  = __logf(1.0f + e) + fmaxf(z, 0.0f); // softplus(z) = bce
            float alw = t ? 0.25f : 0.75f;
            csum += alw * sig * sig * sp;
        }
        cls_sum += live * csum;
    }

    // ---- Reduce: wave shuffle -> LDS -> per-block partial (no atomics) ----
#pragma unroll
    for (int off = 32; off > 0; off >>= 1) {
        loc_sum += __shfl_down(loc_sum, off);
        cls_sum += __shfl_down(cls_sum, off);
        npos    += __shfl_down(npos, off);
    }
    const int lane = threadIdx.x & 63;
    const int wid  = threadIdx.x >> 6;
    if (lane == 0) {
        sred[0][wid] = loc_sum;
        sred[1][wid] = cls_sum;
        sred[2][wid] = npos;
    }
    __syncthreads();
    if (threadIdx.x == 0) {
        float l = 0.0f, c = 0.0f, n = 0.0f;
#pragma unroll
        for (int i = 0; i < kBlock / 64; ++i) {
            l += sred[0][i]; c += sred[1][i]; n += sred[2][i];
        }
        const int bid = blockIdx.y * gridDim.x + blockIdx.x;
        partial[3 * bid + 0] = l;
        partial[3 * bid + 1] = c;
        partial[3 * bid + 2] = n;
    }
}

__global__ __launch_bounds__(1024) void retina_final(
    const float* __restrict__ partial, float* __restrict__ out)
{
    __shared__ float s[3][16];
    float l = 0.0f, c = 0.0f, n = 0.0f;
    for (int i = threadIdx.x; i < kNBlocks; i += 1024) {
        l += partial[3 * i + 0];
        c += partial[3 * i + 1];
        n += partial[3 * i + 2];
    }
#pragma unroll
    for (int off = 32; off > 0; off >>= 1) {
        l += __shfl_down(l, off);
        c += __shfl_down(c, off);
        n += __shfl_down(n, off);
    }
    const int lane = threadIdx.x & 63;
    const int wid  = threadIdx.x >> 6;
    if (lane == 0) { s[0][wid] = l; s[1][wid] = c; s[2][wid] = n; }
    __syncthreads();
    if (threadIdx.x == 0) {
        float L = 0.0f, C = 0.0f, N = 0.0f;
#pragma unroll
        for (int i = 0; i < 16; ++i) { L += s[0][i]; C += s[1][i]; N += s[2][i]; }
        float np  = fmaxf(1.0f, N);
        float inv = 1.0f / np;
        out[0] = (L + C) * inv;
        out[1] = L * inv;
        out[2] = C * inv;
    }
}

}  // namespace

extern "C" void kernel_launch(void* const* d_in, const int* in_sizes, int n_in,
                              void* d_out, int out_size, void* d_ws, size_t ws_size,
                              hipStream_t stream) {
    const float* loc_preds = (const float*)d_in[0];
    const float* cls_preds = (const float*)d_in[1];
    const float* iou_boxes = (const float*)d_in[2];
    const float* targets   = (const float*)d_in[3];
    float* out     = (float*)d_out;
    float* partial = (float*)d_ws;   // 4096*3 floats, fully overwritten each call

    dim3 grid(kGridX, kB);
    retina_main<<<grid, kBlock, 0, stream>>>(loc_preds, cls_preds, iou_boxes, targets, partial);
    retina_final<<<1, 1024, 0, stream>>>(partial, out);
}